// Round 1
// baseline (58.092 us; speedup 1.0000x reference)
//
#include <hip/hip_runtime.h>
#include <hip/hip_bf16.h>
#include <math.h>

#define EPSF 1e-8f

constexpr int N_OBJ  = 8192;
constexpr int M_SR   = 4096;
constexpr int N_FACE = 2048;

constexpr int THREADS     = 256;
constexpr int SUBS        = 16;                    // threads per point
constexpr int PTS_PER_BLK = THREADS / SUBS;        // 16
constexpr int NBLK        = N_OBJ / PTS_PER_BLK;   // 512
constexpr int FTILE       = 1024;                  // faces per LDS tile

struct FaceTile {
    float fnx[FTILE], fny[FTILE], fnz[FTILE], nf[FTILE];
    float v0x[FTILE], v0y[FTILE], v0z[FTILE];
    float v1x[FTILE], v1y[FTILE], v1z[FTILE];
    float v2x[FTILE], v2y[FTILE], v2z[FTILE];
};
struct SrTile {
    float sx[M_SR], sy[M_SR], sz[M_SR];
};
union Shm {
    SrTile   sr;   // 48 KB
    FaceTile ft;   // 52 KB
};

__global__ __launch_bounds__(THREADS) void sr_main(
    const float* __restrict__ obj, const float* __restrict__ srp,
    const float* __restrict__ verts, const int* __restrict__ faces,
    const float* __restrict__ fnorm, float* __restrict__ out,
    float* __restrict__ accum)
{
    __shared__ Shm sm;
    __shared__ float wsum[THREADS / 64];

    const int tid     = threadIdx.x;
    const int p_local = tid >> 4;      // 0..15
    const int sub     = tid & 15;      // 0..15
    const int n       = blockIdx.x * PTS_PER_BLK + p_local;

    // ---------- Phase A: stage sr points (SoA) ----------
    for (int i = tid; i < M_SR; i += THREADS) {
        sm.sr.sx[i] = srp[3 * i + 0];
        sm.sr.sy[i] = srp[3 * i + 1];
        sm.sr.sz[i] = srp[3 * i + 2];
    }
    __syncthreads();

    const float ox = obj[3 * n + 0], oy = obj[3 * n + 1], oz = obj[3 * n + 2];

    // ---------- NN argmin (first-min tie-break) ----------
    float best = 3.4e38f;
    int   bidx = 0x7fffffff;
    for (int j = 0; j < M_SR / SUBS; ++j) {
        int   s  = j * SUBS + sub;
        float dx = ox - sm.sr.sx[s];
        float dy = oy - sm.sr.sy[s];
        float dz = oz - sm.sr.sz[s];
        float d2 = dx * dx + dy * dy + dz * dz;
        if (d2 < best) { best = d2; bidx = s; }   // strictly-less keeps first index per thread
    }
    for (int off = 1; off < SUBS; off <<= 1) {
        float od = __shfl_xor(best, off);
        int   oi = __shfl_xor(bidx, off);
        if (od < best || (od == best && oi < bidx)) { best = od; bidx = oi; }
    }

    const float rdx = sm.sr.sx[bidx] - ox;
    const float rdy = sm.sr.sy[bidx] - oy;
    const float rdz = sm.sr.sz[bidx] - oz;

    if (sub == 0) {
        float nd = sqrtf(best + EPSF);
        // cmap = 1 - 2*(sigmoid(100*nd) - 0.5) = 2*sigmoid(-100*nd)
        out[1 + n] = 2.0f / (1.0f + expf(100.0f * nd));
    }
    __syncthreads();   // done with sr LDS; repurpose for faces

    // ---------- Phase B: ray-triangle hit parity ----------
    int hits = 0;
    for (int tile = 0; tile < N_FACE / FTILE; ++tile) {
        for (int i = tid; i < FTILE; i += THREADS) {
            int f  = tile * FTILE + i;
            int i0 = faces[3 * f + 0], i1 = faces[3 * f + 1], i2 = faces[3 * f + 2];
            float ax = verts[3 * i0 + 0], ay = verts[3 * i0 + 1], az = verts[3 * i0 + 2];
            float bx = verts[3 * i1 + 0], by = verts[3 * i1 + 1], bz = verts[3 * i1 + 2];
            float cx = verts[3 * i2 + 0], cy = verts[3 * i2 + 1], cz = verts[3 * i2 + 2];
            float fx = fnorm[3 * f + 0], fy = fnorm[3 * f + 1], fz = fnorm[3 * f + 2];
            sm.ft.fnx[i] = fx; sm.ft.fny[i] = fy; sm.ft.fnz[i] = fz;
            sm.ft.nf[i]  = fx * ax + fy * ay + fz * az;
            sm.ft.v0x[i] = ax; sm.ft.v0y[i] = ay; sm.ft.v0z[i] = az;
            sm.ft.v1x[i] = bx; sm.ft.v1y[i] = by; sm.ft.v1z[i] = bz;
            sm.ft.v2x[i] = cx; sm.ft.v2y[i] = cy; sm.ft.v2z[i] = cz;
        }
        __syncthreads();

        for (int j = 0; j < FTILE / SUBS; ++j) {
            int   f    = j * SUBS + sub;
            float fx   = sm.ft.fnx[f], fy = sm.ft.fny[f], fz = sm.ft.fnz[f];
            float den  = fx * rdx + fy * rdy + fz * rdz;
            float aden = fabsf(den);
            float t    = (sm.ft.nf[f] - (fx * ox + fy * oy + fz * oz)) / den;
            float px   = ox + t * rdx;
            float py   = oy + t * rdy;
            float pz   = oz + t * rdz;

            float v0x = sm.ft.v0x[f], v0y = sm.ft.v0y[f], v0z = sm.ft.v0z[f];
            float v1x = sm.ft.v1x[f], v1y = sm.ft.v1y[f], v1z = sm.ft.v1z[f];
            float v2x = sm.ft.v2x[f], v2y = sm.ft.v2y[f], v2z = sm.ft.v2z[f];

            // edge i: c = cross(vj - vi, p - vi); inside &= dot(c, fn) >= 0
            float ex, ey, ez, qx, qy, qz, cxv, cyv, czv;
            ex = v1x - v0x; ey = v1y - v0y; ez = v1z - v0z;
            qx = px - v0x;  qy = py - v0y;  qz = pz - v0z;
            cxv = ey * qz - ez * qy; cyv = ez * qx - ex * qz; czv = ex * qy - ey * qx;
            bool in0 = (cxv * fx + cyv * fy + czv * fz) >= 0.0f;

            ex = v2x - v1x; ey = v2y - v1y; ez = v2z - v1z;
            qx = px - v1x;  qy = py - v1y;  qz = pz - v1z;
            cxv = ey * qz - ez * qy; cyv = ez * qx - ex * qz; czv = ex * qy - ey * qx;
            bool in1 = (cxv * fx + cyv * fy + czv * fz) >= 0.0f;

            ex = v0x - v2x; ey = v0y - v2y; ez = v0z - v2z;
            qx = px - v2x;  qy = py - v2y;  qz = pz - v2z;
            cxv = ey * qz - ez * qy; cyv = ez * qx - ex * qz; czv = ex * qy - ey * qx;
            bool in2 = (cxv * fx + cyv * fy + czv * fz) >= 0.0f;

            hits += (in0 && in1 && in2 && (t >= 0.0f) && (aden >= EPSF)) ? 1 : 0;
        }
        __syncthreads();   // protect LDS before next tile staging
    }

    // ---------- parity + pen accumulation ----------
    for (int off = 1; off < SUBS; off <<= 1) hits += __shfl_xor(hits, off);

    float contrib = ((hits & 1) && sub == 0) ? (rdx * rdx + rdy * rdy + rdz * rdz) : 0.0f;
    contrib += __shfl_xor(contrib, 16);
    contrib += __shfl_xor(contrib, 32);

    const int wave = tid >> 6;
    if ((tid & 63) == 0) wsum[wave] = contrib;
    __syncthreads();
    if (tid == 0) {
        float s = 0.0f;
        for (int w = 0; w < THREADS / 64; ++w) s += wsum[w];
        atomicAdd(accum, s);
    }
}

__global__ void sr_fin(const float* __restrict__ accum, float* __restrict__ out)
{
    out[0] = sqrtf(*accum);
}

extern "C" void kernel_launch(void* const* d_in, const int* in_sizes, int n_in,
                              void* d_out, int out_size, void* d_ws, size_t ws_size,
                              hipStream_t stream)
{
    const float* obj   = (const float*)d_in[0];
    const float* srp   = (const float*)d_in[1];
    const float* verts = (const float*)d_in[2];
    const int*   faces = (const int*)d_in[3];
    const float* fnorm = (const float*)d_in[4];
    float*       out   = (float*)d_out;
    float*       accum = (float*)d_ws;

    hipMemsetAsync(d_ws, 0, sizeof(float), stream);
    sr_main<<<NBLK, THREADS, 0, stream>>>(obj, srp, verts, faces, fnorm, out, accum);
    sr_fin<<<1, 1, 0, stream>>>(accum, out);
}

// Round 2
// 54.222 us; speedup vs baseline: 1.0714x; 1.0714x over previous
//
#include <hip/hip_runtime.h>
#include <hip/hip_bf16.h>
#include <math.h>

#define EPSF 1e-8f

constexpr int N_OBJ  = 8192;
constexpr int M_SR   = 4096;
constexpr int N_FACE = 2048;

constexpr int THREADS = 256;
constexpr int PPB     = 8;               // points per block
constexpr int NBLK    = N_OBJ / PPB;     // 1024
constexpr int FTILE   = 512;             // faces per LDS tile
constexpr int SRTILE  = 2048;            // sr points per LDS tile

// ws layout (floats): [0] accum, [16..] face SoA rows fd[k*N_FACE + f], k=0..15
// row order: fnx fny fnz nf | g0x g0y g0z h0 | g1x g1y g1z h1 | g2x g2y g2z h2

__global__ void face_setup(const float* __restrict__ verts,
                           const int* __restrict__ faces,
                           const float* __restrict__ fnorm,
                           float* __restrict__ fd)
{
    int f = blockIdx.x * 256 + threadIdx.x;
    if (f >= N_FACE) return;
    int i0 = faces[3 * f + 0], i1 = faces[3 * f + 1], i2 = faces[3 * f + 2];
    float ax = verts[3 * i0 + 0], ay = verts[3 * i0 + 1], az = verts[3 * i0 + 2];
    float bx = verts[3 * i1 + 0], by = verts[3 * i1 + 1], bz = verts[3 * i1 + 2];
    float cx = verts[3 * i2 + 0], cy = verts[3 * i2 + 1], cz = verts[3 * i2 + 2];
    float fx = fnorm[3 * f + 0], fy = fnorm[3 * f + 1], fz = fnorm[3 * f + 2];

    float nf = fx * ax + fy * ay + fz * az;

    // g_i = fn x e_i ; h_i = g_i . v_i
    float e0x = bx - ax, e0y = by - ay, e0z = bz - az;
    float g0x = fy * e0z - fz * e0y, g0y = fz * e0x - fx * e0z, g0z = fx * e0y - fy * e0x;
    float h0  = g0x * ax + g0y * ay + g0z * az;

    float e1x = cx - bx, e1y = cy - by, e1z = cz - bz;
    float g1x = fy * e1z - fz * e1y, g1y = fz * e1x - fx * e1z, g1z = fx * e1y - fy * e1x;
    float h1  = g1x * bx + g1y * by + g1z * bz;

    float e2x = ax - cx, e2y = ay - cy, e2z = az - cz;
    float g2x = fy * e2z - fz * e2y, g2y = fz * e2x - fx * e2z, g2z = fx * e2y - fy * e2x;
    float h2  = g2x * cx + g2y * cy + g2z * cz;

    fd[0  * N_FACE + f] = fx;  fd[1  * N_FACE + f] = fy;
    fd[2  * N_FACE + f] = fz;  fd[3  * N_FACE + f] = nf;
    fd[4  * N_FACE + f] = g0x; fd[5  * N_FACE + f] = g0y;
    fd[6  * N_FACE + f] = g0z; fd[7  * N_FACE + f] = h0;
    fd[8  * N_FACE + f] = g1x; fd[9  * N_FACE + f] = g1y;
    fd[10 * N_FACE + f] = g1z; fd[11 * N_FACE + f] = h1;
    fd[12 * N_FACE + f] = g2x; fd[13 * N_FACE + f] = g2y;
    fd[14 * N_FACE + f] = g2z; fd[15 * N_FACE + f] = h2;
}

union Shm {
    float4 s4[SRTILE];        // 32 KB: (sx,sy,sz,|s|^2)
    float  f[16][FTILE];      // 32 KB: face SoA rows
};

__global__ __launch_bounds__(THREADS) void sr_main(
    const float* __restrict__ obj, const float* __restrict__ srp,
    const float* __restrict__ fd, float* __restrict__ out,
    float* __restrict__ accum)
{
    __shared__ Shm sm;
    __shared__ float ptd[PPB][8];   // ox,oy,oz,dx,dy,dz,d2,-
    __shared__ int   cnt[4][PPB];
    __shared__ float pc[PPB];

    const int tid  = threadIdx.x;
    const int w    = tid >> 6;      // wave 0..3
    const int lane = tid & 63;

    // ---------------- Phase A: NN search (2 points per wave) ----------------
    const int pA = 2 * w, pB = 2 * w + 1;
    const int nA = blockIdx.x * PPB + pA;
    const int nB = nA + 1;
    const float oxA = obj[3 * nA], oyA = obj[3 * nA + 1], ozA = obj[3 * nA + 2];
    const float oxB = obj[3 * nB], oyB = obj[3 * nB + 1], ozB = obj[3 * nB + 2];
    const float ooA = oxA * oxA + oyA * oyA + ozA * ozA;
    const float ooB = oxB * oxB + oyB * oyB + ozB * ozB;

    float bestA = 3.4e38f, bestB = 3.4e38f;
    int   biA = 0, biB = 0;

    for (int t0 = 0; t0 < M_SR; t0 += SRTILE) {
        __syncthreads();
        for (int i = tid; i < SRTILE; i += THREADS) {
            float sx = srp[3 * (t0 + i) + 0];
            float sy = srp[3 * (t0 + i) + 1];
            float sz = srp[3 * (t0 + i) + 2];
            sm.s4[i] = make_float4(sx, sy, sz, sx * sx + sy * sy + sz * sz);
        }
        __syncthreads();
        for (int j = 0; j < SRTILE / 64; ++j) {
            int s = j * 64 + lane;
            float4 v = sm.s4[s];
            float mA = v.w - 2.0f * (oxA * v.x + oyA * v.y + ozA * v.z);
            float mB = v.w - 2.0f * (oxB * v.x + oyB * v.y + ozB * v.z);
            if (mA < bestA) { bestA = mA; biA = t0 + s; }
            if (mB < bestB) { bestB = mB; biB = t0 + s; }
        }
    }
    for (int off = 1; off < 64; off <<= 1) {
        float odA = __shfl_xor(bestA, off); int oiA = __shfl_xor(biA, off);
        if (odA < bestA || (odA == bestA && oiA < biA)) { bestA = odA; biA = oiA; }
        float odB = __shfl_xor(bestB, off); int oiB = __shfl_xor(biB, off);
        if (odB < bestB || (odB == bestB && oiB < biB)) { bestB = odB; biB = oiB; }
    }
    if (lane == 0) {
        float d2A = bestA + ooA;
        float dxA = srp[3 * biA] - oxA, dyA = srp[3 * biA + 1] - oyA, dzA = srp[3 * biA + 2] - ozA;
        ptd[pA][0] = oxA; ptd[pA][1] = oyA; ptd[pA][2] = ozA;
        ptd[pA][3] = dxA; ptd[pA][4] = dyA; ptd[pA][5] = dzA;
        ptd[pA][6] = d2A;
        out[1 + nA] = 2.0f / (1.0f + expf(100.0f * sqrtf(d2A + EPSF)));

        float d2B = bestB + ooB;
        float dxB = srp[3 * biB] - oxB, dyB = srp[3 * biB + 1] - oyB, dzB = srp[3 * biB + 2] - ozB;
        ptd[pB][0] = oxB; ptd[pB][1] = oyB; ptd[pB][2] = ozB;
        ptd[pB][3] = dxB; ptd[pB][4] = dyB; ptd[pB][5] = dzB;
        ptd[pB][6] = d2B;
        out[1 + nB] = 2.0f / (1.0f + expf(100.0f * sqrtf(d2B + EPSF)));
    }
    __syncthreads();

    // ---------------- Phase B: ray-triangle parity, KP=8 ----------------
    float pox[PPB], poy[PPB], poz[PPB], pdx[PPB], pdy[PPB], pdz[PPB];
#pragma unroll
    for (int q = 0; q < PPB; ++q) {
        pox[q] = ptd[q][0]; poy[q] = ptd[q][1]; poz[q] = ptd[q][2];
        pdx[q] = ptd[q][3]; pdy[q] = ptd[q][4]; pdz[q] = ptd[q][5];
    }
    int hits[PPB];
#pragma unroll
    for (int q = 0; q < PPB; ++q) hits[q] = 0;

    for (int tile = 0; tile < N_FACE / FTILE; ++tile) {
        __syncthreads();
        for (int i = tid; i < 16 * FTILE / 4; i += THREADS) {
            int k = i >> 7;          // row
            int q = i & 127;         // float4 within row
            ((float4*)&sm.f[k][0])[q] =
                ((const float4*)(fd + k * N_FACE + tile * FTILE))[q];
        }
        __syncthreads();

#pragma unroll
        for (int j = 0; j < FTILE / 256; ++j) {
            int f = j * 256 + w * 64 + lane;   // 0..FTILE-1, lane-consecutive
            float fx  = sm.f[0][f],  fy  = sm.f[1][f],  fz  = sm.f[2][f],  nf = sm.f[3][f];
            float g0x = sm.f[4][f],  g0y = sm.f[5][f],  g0z = sm.f[6][f],  h0 = sm.f[7][f];
            float g1x = sm.f[8][f],  g1y = sm.f[9][f],  g1z = sm.f[10][f], h1 = sm.f[11][f];
            float g2x = sm.f[12][f], g2y = sm.f[13][f], g2z = sm.f[14][f], h2 = sm.f[15][f];
            bool dok = fabsf(fx) >= 0.0f;  // placeholder to keep structure clear
            (void)dok;
#pragma unroll
            for (int q = 0; q < PPB; ++q) {
                float den = fx * pdx[q] + fy * pdy[q] + fz * pdz[q];
                float num = nf - (fx * pox[q] + fy * poy[q] + fz * poz[q]);
                float Px  = den * pox[q] + num * pdx[q];
                float Py  = den * poy[q] + num * pdy[q];
                float Pz  = den * poz[q] + num * pdz[q];
                bool pos = den >= 0.0f;
                bool ok0 = ((g0x * Px + g0y * Py + g0z * Pz - den * h0) >= 0.0f) == pos;
                bool ok1 = ((g1x * Px + g1y * Py + g1z * Pz - den * h1) >= 0.0f) == pos;
                bool ok2 = ((g2x * Px + g2y * Py + g2z * Pz - den * h2) >= 0.0f) == pos;
                bool tok = (num >= 0.0f) == pos;
                bool aok = fabsf(den) >= EPSF;
                hits[q] += (ok0 & ok1 & ok2 & tok & aok) ? 1 : 0;
            }
        }
    }

    // reduce hit counts across the wave
#pragma unroll
    for (int q = 0; q < PPB; ++q) {
        int h = hits[q];
        for (int off = 1; off < 64; off <<= 1) h += __shfl_xor(h, off);
        hits[q] = h;
    }
    if (lane == 0) {
#pragma unroll
        for (int q = 0; q < PPB; ++q) cnt[w][q] = hits[q];
    }
    __syncthreads();

    if (tid < PPB) {
        int tot = cnt[0][tid] + cnt[1][tid] + cnt[2][tid] + cnt[3][tid];
        pc[tid] = (tot & 1) ? ptd[tid][6] : 0.0f;
    }
    __syncthreads();
    if (tid == 0) {
        float s = 0.0f;
#pragma unroll
        for (int q = 0; q < PPB; ++q) s += pc[q];
        atomicAdd(accum, s);
    }
}

__global__ void sr_fin(const float* __restrict__ accum, float* __restrict__ out)
{
    out[0] = sqrtf(*accum);
}

extern "C" void kernel_launch(void* const* d_in, const int* in_sizes, int n_in,
                              void* d_out, int out_size, void* d_ws, size_t ws_size,
                              hipStream_t stream)
{
    const float* obj   = (const float*)d_in[0];
    const float* srp   = (const float*)d_in[1];
    const float* verts = (const float*)d_in[2];
    const int*   faces = (const int*)d_in[3];
    const float* fnorm = (const float*)d_in[4];
    float*       out   = (float*)d_out;
    float*       wsf   = (float*)d_ws;
    float*       accum = wsf;
    float*       fd    = wsf + 16;

    hipMemsetAsync(d_ws, 0, sizeof(float), stream);
    face_setup<<<(N_FACE + 255) / 256, 256, 0, stream>>>(verts, faces, fnorm, fd);
    sr_main<<<NBLK, THREADS, 0, stream>>>(obj, srp, fd, out, accum);
    sr_fin<<<1, 1, 0, stream>>>(accum, out);
}